// Round 1
// baseline (433.245 us; speedup 1.0000x reference)
//
#include <hip/hip_runtime.h>

// Problem: features (1,512,512,256) f32, superpixel (512,512) int, w_node (21,256) f32
//   out[sp][c] = (mean over pixels with label sp of features[pixel]) . w_node[c]
// NUM_SP = 1024, F = 256, C = 21, n_pix = 262144.
//
// Strategy: counting-sort pixel indices by superpixel label (hist -> scan ->
// scatter), then 1 block per superpixel gathers its rows (1 KB contiguous each,
// wave-wide float4 loads), accumulates in registers, and fuses the /count and
// the 21-class linear in the epilogue. No fp32 atomics anywhere.

#define NSP 1024
#define FDIM 256

__global__ void hist_kernel(const int* __restrict__ sp, int n,
                            int* __restrict__ hist) {
    __shared__ int lh[NSP];
    for (int i = threadIdx.x; i < NSP; i += blockDim.x) lh[i] = 0;
    __syncthreads();
    for (int i = blockIdx.x * blockDim.x + threadIdx.x; i < n;
         i += gridDim.x * blockDim.x)
        atomicAdd(&lh[sp[i]], 1);
    __syncthreads();
    for (int i = threadIdx.x; i < NSP; i += blockDim.x) {
        int v = lh[i];
        if (v) atomicAdd(&hist[i], v);
    }
}

// 1 block, NSP threads. Exclusive prefix sum (Hillis-Steele in LDS).
__global__ void scan_kernel(const int* __restrict__ hist,
                            int* __restrict__ starts,
                            int* __restrict__ cursors) {
    __shared__ int buf[NSP];
    int t = threadIdx.x;
    int v = hist[t];
    buf[t] = v;
    __syncthreads();
    for (int off = 1; off < NSP; off <<= 1) {
        int add = (t >= off) ? buf[t - off] : 0;
        __syncthreads();
        buf[t] += add;
        __syncthreads();
    }
    int st = buf[t] - v;  // exclusive prefix
    starts[t] = st;
    cursors[t] = st;
}

__global__ void scatter_kernel(const int* __restrict__ sp, int n,
                               int* __restrict__ cursors,
                               int* __restrict__ order) {
    for (int i = blockIdx.x * blockDim.x + threadIdx.x; i < n;
         i += gridDim.x * blockDim.x) {
        int pos = atomicAdd(&cursors[sp[i]], 1);
        order[pos] = i;
    }
}

// grid = NSP blocks x 256 threads (4 waves). Block b owns superpixel b.
__global__ __launch_bounds__(256) void reduce_matmul_kernel(
    const float* __restrict__ feats, const int* __restrict__ order,
    const int* __restrict__ starts, const int* __restrict__ hist,
    const float* __restrict__ w, float* __restrict__ out, int C) {
    const int b = blockIdx.x;
    const int tid = (int)threadIdx.x;
    const int lane = tid & 63;
    const int wave = tid >> 6;

    const int start = starts[b];
    const int n = hist[b];
    const int end = start + n;

    // Each lane covers feature columns [4*lane, 4*lane+4). Two accumulators
    // + 4-row unroll keep 4 independent 16B loads in flight per wave.
    float a0x = 0.f, a0y = 0.f, a0z = 0.f, a0w = 0.f;
    float a1x = 0.f, a1y = 0.f, a1z = 0.f, a1w = 0.f;

    int base = start + wave * 4;  // wave strides by 16 rows (4 waves x 4 rows)
    for (; base + 3 < end; base += 16) {
        int i0 = order[base + 0];
        int i1 = order[base + 1];
        int i2 = order[base + 2];
        int i3 = order[base + 3];
        float4 v0 = ((const float4*)(feats + (size_t)i0 * FDIM))[lane];
        float4 v1 = ((const float4*)(feats + (size_t)i1 * FDIM))[lane];
        float4 v2 = ((const float4*)(feats + (size_t)i2 * FDIM))[lane];
        float4 v3 = ((const float4*)(feats + (size_t)i3 * FDIM))[lane];
        a0x += v0.x; a0y += v0.y; a0z += v0.z; a0w += v0.w;
        a1x += v1.x; a1y += v1.y; a1z += v1.z; a1w += v1.w;
        a0x += v2.x; a0y += v2.y; a0z += v2.z; a0w += v2.w;
        a1x += v3.x; a1y += v3.y; a1z += v3.z; a1w += v3.w;
    }
    // Tail: only the wave owning the partial 4-row group enters.
    for (; base < end; ++base) {
        int idx = order[base];
        float4 v = ((const float4*)(feats + (size_t)idx * FDIM))[lane];
        a0x += v.x; a0y += v.y; a0z += v.z; a0w += v.w;
    }
    a0x += a1x; a0y += a1y; a0z += a1z; a0w += a1w;

    // Cross-wave combine in LDS (1024 LDS atomics/block — negligible).
    __shared__ float fsum[FDIM];
    fsum[tid] = 0.f;  // blockDim == FDIM == 256
    __syncthreads();
    atomicAdd(&fsum[lane * 4 + 0], a0x);
    atomicAdd(&fsum[lane * 4 + 1], a0y);
    atomicAdd(&fsum[lane * 4 + 2], a0z);
    atomicAdd(&fsum[lane * 4 + 3], a0w);
    __syncthreads();

    const float scale = (n > 0) ? 1.0f / (float)n : 0.0f;
    float4 m = ((const float4*)fsum)[lane];
    m.x *= scale; m.y *= scale; m.z *= scale; m.w *= scale;

    // Fused linear: waves split the C classes; shuffle-reduce each dot.
    for (int c = wave; c < C; c += 4) {
        float4 w4 = ((const float4*)(w + (size_t)c * FDIM))[lane];
        float p = m.x * w4.x + m.y * w4.y + m.z * w4.z + m.w * w4.w;
        #pragma unroll
        for (int off = 32; off > 0; off >>= 1) p += __shfl_down(p, off, 64);
        if (lane == 0) out[b * C + c] = p;
    }
}

extern "C" void kernel_launch(void* const* d_in, const int* in_sizes, int n_in,
                              void* d_out, int out_size, void* d_ws,
                              size_t ws_size, hipStream_t stream) {
    const float* feats = (const float*)d_in[0];
    const int* sp = (const int*)d_in[1];
    const float* w = (const float*)d_in[2];
    float* out = (float*)d_out;

    const int n_pix = in_sizes[1];                 // 262144
    const int C = in_sizes[2] / FDIM;              // 21

    // Workspace layout (ws poisoned 0xAA each call -> re-init what we need):
    //   [0,4K)      hist   (int[1024])  -- memset to 0
    //   [4K,8K)     starts (int[1024])  -- written by scan
    //   [8K,12K)    cursors(int[1024])  -- written by scan
    //   [12K, +1MB) order  (int[n_pix]) -- fully written by scatter
    char* ws = (char*)d_ws;
    int* hist = (int*)(ws);
    int* starts = (int*)(ws + 4096);
    int* cursors = (int*)(ws + 8192);
    int* order = (int*)(ws + 12288);

    hipMemsetAsync(hist, 0, NSP * sizeof(int), stream);

    hist_kernel<<<256, 256, 0, stream>>>(sp, n_pix, hist);
    scan_kernel<<<1, NSP, 0, stream>>>(hist, starts, cursors);
    scatter_kernel<<<512, 256, 0, stream>>>(sp, n_pix, cursors, order);
    reduce_matmul_kernel<<<NSP, 256, 0, stream>>>(feats, order, starts, hist,
                                                  w, out, C);
}

// Round 2
// 389.857 us; speedup vs baseline: 1.1113x; 1.1113x over previous
//
#include <hip/hip_runtime.h>

// Problem: features (1,512,512,256) f32, superpixel (512,512) int, w_node (21,256) f32
//   out[sp][c] = (mean over pixels with label sp of features[pixel]) . w_node[c]
// NUM_SP = 1024, F = 256, C = 21, n_pix = 262144.
//
// Pipeline (ZERO global atomics):
//   k1 hist:    128 blocks, per-block LDS histogram -> private slab[b][label] (plain stores)
//   k2 scan:    1 block x 1024 thr: in-place exclusive per-block prefix down the slab
//               column + exclusive scan of label totals -> starts, counts
//   k3 scatter: 128 blocks, LDS cursors = slab[b][t] + starts[t]; LDS atomics for rank
//   k4 reduce:  1 block per superpixel; caches its order-slice in LDS, gathers rows
//               (1 KB contiguous, wave-wide float4), register accum, fused /count + linear

#define NSP 1024
#define FDIM 256
#define NBLK 128      // chunk blocks for hist/scatter
#define IDX_CAP 4096  // LDS order-slice capacity per reduce block (mean n=256)

__global__ __launch_bounds__(256) void hist_kernel(
    const int* __restrict__ sp, int n, int* __restrict__ slab) {
    __shared__ int lh[NSP];
    const int b = blockIdx.x;
    for (int t = threadIdx.x; t < NSP; t += blockDim.x) lh[t] = 0;
    __syncthreads();
    const int chunk = (n + NBLK - 1) / NBLK;
    const int begin = b * chunk;
    const int end = min(begin + chunk, n);
    for (int i = begin + (int)threadIdx.x; i < end; i += blockDim.x)
        atomicAdd(&lh[sp[i]], 1);
    __syncthreads();
    for (int t = threadIdx.x; t < NSP; t += blockDim.x)
        slab[b * NSP + t] = lh[t];  // coalesced plain store, no atomics
}

// 1 block x NSP threads. Converts slab to per-(block,label) exclusive prefixes,
// computes label starts (exclusive scan of totals) and counts.
__global__ __launch_bounds__(NSP) void scan_kernel(
    int* __restrict__ slab, int* __restrict__ starts, int* __restrict__ counts) {
    __shared__ int buf[NSP];
    const int t = threadIdx.x;
    int running = 0;
    for (int b = 0; b < NBLK; ++b) {          // coalesced across threads per b
        int v = slab[b * NSP + t];
        slab[b * NSP + t] = running;          // exclusive prefix within label
        running += v;
    }
    counts[t] = running;
    buf[t] = running;
    __syncthreads();
    for (int off = 1; off < NSP; off <<= 1) {  // Hillis-Steele inclusive scan
        int add = (t >= off) ? buf[t - off] : 0;
        __syncthreads();
        buf[t] += add;
        __syncthreads();
    }
    starts[t] = buf[t] - running;  // exclusive
}

__global__ __launch_bounds__(256) void scatter_kernel(
    const int* __restrict__ sp, int n, const int* __restrict__ slab,
    const int* __restrict__ starts, int* __restrict__ order) {
    __shared__ int cursor[NSP];
    const int b = blockIdx.x;
    for (int t = threadIdx.x; t < NSP; t += blockDim.x)
        cursor[t] = slab[b * NSP + t] + starts[t];
    __syncthreads();
    const int chunk = (n + NBLK - 1) / NBLK;
    const int begin = b * chunk;
    const int end = min(begin + chunk, n);
    for (int i = begin + (int)threadIdx.x; i < end; i += blockDim.x) {
        int pos = atomicAdd(&cursor[sp[i]], 1);  // LDS atomic only
        order[pos] = i;
    }
}

// grid = NSP blocks x 256 threads (4 waves). Block b owns superpixel b.
__global__ __launch_bounds__(256) void reduce_matmul_kernel(
    const float* __restrict__ feats, const int* __restrict__ order,
    const int* __restrict__ starts, const int* __restrict__ counts,
    const float* __restrict__ w, float* __restrict__ out, int C) {
    __shared__ int idx_lds[IDX_CAP];
    __shared__ float fsum[FDIM];
    const int b = blockIdx.x;
    const int tid = (int)threadIdx.x;
    const int lane = tid & 63;
    const int wave = tid >> 6;

    const int start = starts[b];
    const int n = counts[b];
    const bool cached = (n <= IDX_CAP);

    if (cached)
        for (int i = tid; i < n; i += 256) idx_lds[i] = order[start + i];
    fsum[tid] = 0.f;  // blockDim == FDIM == 256
    __syncthreads();

    // Lane covers feature cols [4*lane, 4*lane+4). Wave strides 16 rows
    // (4 waves x 4 rows); 4 independent 1 KB row-gathers in flight per wave,
    // indices served from LDS (no global latency in the chain).
    float a0x = 0.f, a0y = 0.f, a0z = 0.f, a0w = 0.f;
    float a1x = 0.f, a1y = 0.f, a1z = 0.f, a1w = 0.f;

    int pos = wave * 4;
    for (; pos + 3 < n; pos += 16) {
        int i0, i1, i2, i3;
        if (cached) {
            i0 = idx_lds[pos + 0]; i1 = idx_lds[pos + 1];
            i2 = idx_lds[pos + 2]; i3 = idx_lds[pos + 3];
        } else {
            i0 = order[start + pos + 0]; i1 = order[start + pos + 1];
            i2 = order[start + pos + 2]; i3 = order[start + pos + 3];
        }
        float4 v0 = ((const float4*)(feats + (size_t)i0 * FDIM))[lane];
        float4 v1 = ((const float4*)(feats + (size_t)i1 * FDIM))[lane];
        float4 v2 = ((const float4*)(feats + (size_t)i2 * FDIM))[lane];
        float4 v3 = ((const float4*)(feats + (size_t)i3 * FDIM))[lane];
        a0x += v0.x; a0y += v0.y; a0z += v0.z; a0w += v0.w;
        a1x += v1.x; a1y += v1.y; a1z += v1.z; a1w += v1.w;
        a0x += v2.x; a0y += v2.y; a0z += v2.z; a0w += v2.w;
        a1x += v3.x; a1y += v3.y; a1z += v3.z; a1w += v3.w;
    }
    for (; pos < n; ++pos) {  // tail rows (only the owning wave enters)
        int idx = cached ? idx_lds[pos] : order[start + pos];
        float4 v = ((const float4*)(feats + (size_t)idx * FDIM))[lane];
        a0x += v.x; a0y += v.y; a0z += v.z; a0w += v.w;
    }
    a0x += a1x; a0y += a1y; a0z += a1z; a0w += a1w;

    // Cross-wave combine (1024 LDS atomics/block — negligible).
    atomicAdd(&fsum[lane * 4 + 0], a0x);
    atomicAdd(&fsum[lane * 4 + 1], a0y);
    atomicAdd(&fsum[lane * 4 + 2], a0z);
    atomicAdd(&fsum[lane * 4 + 3], a0w);
    __syncthreads();

    const float scale = (n > 0) ? 1.0f / (float)n : 0.0f;
    float4 m = ((const float4*)fsum)[lane];
    m.x *= scale; m.y *= scale; m.z *= scale; m.w *= scale;

    // Fused linear: waves split the C classes; shuffle-reduce each dot.
    for (int c = wave; c < C; c += 4) {
        float4 w4 = ((const float4*)(w + (size_t)c * FDIM))[lane];
        float p = m.x * w4.x + m.y * w4.y + m.z * w4.z + m.w * w4.w;
        #pragma unroll
        for (int off = 32; off > 0; off >>= 1) p += __shfl_down(p, off, 64);
        if (lane == 0) out[b * C + c] = p;
    }
}

extern "C" void kernel_launch(void* const* d_in, const int* in_sizes, int n_in,
                              void* d_out, int out_size, void* d_ws,
                              size_t ws_size, hipStream_t stream) {
    const float* feats = (const float*)d_in[0];
    const int* sp = (const int*)d_in[1];
    const float* w = (const float*)d_in[2];
    float* out = (float*)d_out;

    const int n_pix = in_sizes[1];     // 262144
    const int C = in_sizes[2] / FDIM;  // 21

    // Workspace layout (every word below is fully written before read — no
    // memset needed despite 0xAA poison):
    //   [0, 512K)        slab   (int[NBLK][NSP])
    //   [512K, +4K)      starts (int[NSP])
    //   [516K, +4K)      counts (int[NSP])
    //   [520K, +1M)      order  (int[n_pix])
    char* ws = (char*)d_ws;
    int* slab = (int*)(ws);
    int* starts = (int*)(ws + 512 * 1024);
    int* counts = (int*)(ws + 516 * 1024);
    int* order = (int*)(ws + 520 * 1024);

    hist_kernel<<<NBLK, 256, 0, stream>>>(sp, n_pix, slab);
    scan_kernel<<<1, NSP, 0, stream>>>(slab, starts, counts);
    scatter_kernel<<<NBLK, 256, 0, stream>>>(sp, n_pix, slab, starts, order);
    reduce_matmul_kernel<<<NSP, 256, 0, stream>>>(feats, order, starts, counts,
                                                  w, out, C);
}